// Round 7
// baseline (582.706 us; speedup 1.0000x reference)
//
#include <hip/hip_runtime.h>

#define BH 16
#define L 2048
#define D 64
#define QB 64                 // rows per block (16 per wave x 4 waves)
#define KB 64
#define NKT (L / KB)
#define SCALE 0.125f
#define MASK_FILL -65504.0f

typedef __bf16 bf16x8 __attribute__((ext_vector_type(8)));
typedef float f32x4 __attribute__((ext_vector_type(4)));

__device__ __forceinline__ unsigned f2bf(float f) {
    union { float f; unsigned u; } x; x.f = f;
    return (x.u + 0x7FFFu + ((x.u >> 16) & 1u)) >> 16;   // RNE
}
__device__ __forceinline__ float bf2f(unsigned short h) {
    union { unsigned u; float f; } x; x.u = ((unsigned)h) << 16;
    return x.f;
}

// ========================= pre-pass kernel (K/V only) =====================
// blocks [0,1024): K fp32 -> bf16 chunk-swizzled
// blocks [1024,1536): V fp32 -> bf16 transposed+tiled
// (mask processing moved INTO sdpa_main, pipelined against pass-1 compute)
extern "C" __global__ __launch_bounds__(256)
void prep(const float* __restrict__ k, const float* __restrict__ v,
          uint4* __restrict__ wsK, uint4* __restrict__ wsVt)
{
    __shared__ float sT[64 * 68];                 // used by preV branch only
    const int b = blockIdx.x;
    const int t = threadIdx.x;

    if (b < 1024) {
        // ---- preK ----
        int idx = b * 256 + t;                    // 0..262143 chunks
        int c   = idx & 7;
        int key = (idx >> 3) & (L - 1);
        int bh  = idx >> 14;
        const float4* src = (const float4*)(k + ((size_t)(bh * L + key) * D + c * 8));
        float4 a = src[0], bb = src[1];
        uint4 o;
        o.x = f2bf(a.x)  | (f2bf(a.y)  << 16);
        o.y = f2bf(a.z)  | (f2bf(a.w)  << 16);
        o.z = f2bf(bb.x) | (f2bf(bb.y) << 16);
        o.w = f2bf(bb.z) | (f2bf(bb.w) << 16);
        wsK[(size_t)(bh * L + key) * 8 + (c ^ (key & 7))] = o;
    } else {
        // ---- preV ----
        int bb = b - 1024;                        // 16*32 tiles
        int bh = bb >> 5, kt = bb & 31;
        const float4* src = (const float4*)(v + ((size_t)bh * L + kt * 64) * D);
        #pragma unroll
        for (int i = 0; i < 4; ++i) {
            int i4 = i * 256 + t;                 // 1024 float4s = 64x64 tile
            int key = i4 >> 4, c4 = i4 & 15;
            float4 val = src[i4];
            *(float4*)&sT[key * 68 + c4 * 4] = val;
        }
        __syncthreads();
        int d = t >> 2, cg = t & 3;
        #pragma unroll
        for (int j = 0; j < 2; ++j) {
            int c = cg + j * 4;                   // key-chunk 0..7
            unsigned pk[4];
            #pragma unroll
            for (int e = 0; e < 4; ++e) {
                float x0 = sT[(c * 8 + e * 2    ) * 68 + d];
                float x1 = sT[(c * 8 + e * 2 + 1) * 68 + d];
                pk[e] = f2bf(x0) | (f2bf(x1) << 16);
            }
            wsVt[((size_t)(bh * 32 + kt) * 64 + d) * 8 + (c ^ (d & 7))] =
                make_uint4(pk[0], pk[1], pk[2], pk[3]);
        }
    }
}

// ============================== main kernel ================================
// Round-7 = round-6 resubmission (round-6 bench died with an infra-level
// container error before producing counters; kernel re-audited for fault /
// hang hazards — none found).
//  * r5 wave-autonomous structure (barrier-free, per-wave LDS P transpose,
//    full-key tiles per wave, 2 blocks/CU)
//  * pass 1 stages RAW int32 mask tiles (wave-private 16 rows x 64 cols/kt)
//    into LDS via global_load_lds (16 insts/kt, zero VGPR), triple-buffered
//    3 kt deep (~900cy HBM cover); consume = 16 conflict-free ds_read_b32
//    (row stride 68 words -> worst 2-way = free). Bits accumulate in mb[16]
//    VGPRs for pass 2. The 256MB mask stream now OVERLAPS pass-1 compute
//    instead of serializing in prep.
//  * s_waitcnt vmcnt(32) before consume: 72 VMEM ops issued at/after
//    stage(kt) start, in-order retirement -> <=32 outstanding guarantees
//    stage(kt) landed; cannot deadlock (no-op if fewer in flight).
// LDS: 4*3*16*68*4 = 52.2KB mask + 9.2KB sP = 61.4KB -> 2 blocks/CU.

struct KF { bf16x8 f[8]; };   // one 64-key x 64-k tile fragment set (static idx)

extern "C" __global__ __launch_bounds__(256, 2)
void sdpa_main(const float* __restrict__ q, const uint4* __restrict__ gKall,
               const uint4* __restrict__ gVall, const int* __restrict__ mask,
               float* __restrict__ out, float* __restrict__ attn)
{
    __shared__ unsigned sM[4][3][16 * 68];        // [wave][buf][row][col(pad 68)]
    __shared__ unsigned short sP[4][2][16 * 72];  // [wave][buf][row][col(pad)]

    const int tid = threadIdx.x, lane = tid & 63, w = tid >> 6;
    const int quad = lane >> 4, l15 = lane & 15;
    const int p = blockIdx.x, bh = p & 15, qb = p >> 4;
    const int row0 = qb * QB + w * 16;            // wave's first q-row

    const uint4* gK = gKall + (size_t)bh * L * 8;
    const uint4* gV = gVall + (size_t)bh * L * 8;

    // ---- Q A-fragments (row = l15), pre-scaled by 0.125 (exact) ----
    const float* Qp = q + (size_t)(bh * L + row0 + l15) * D + quad * 8;
    float4 qv0 = *(const float4*)(Qp);
    float4 qv1 = *(const float4*)(Qp + 4);
    float4 qv2 = *(const float4*)(Qp + 32);
    float4 qv3 = *(const float4*)(Qp + 36);
    union { bf16x8 v; unsigned short s[8]; } qa0u, qa1u;
    qa0u.s[0] = f2bf(qv0.x * SCALE); qa0u.s[1] = f2bf(qv0.y * SCALE);
    qa0u.s[2] = f2bf(qv0.z * SCALE); qa0u.s[3] = f2bf(qv0.w * SCALE);
    qa0u.s[4] = f2bf(qv1.x * SCALE); qa0u.s[5] = f2bf(qv1.y * SCALE);
    qa0u.s[6] = f2bf(qv1.z * SCALE); qa0u.s[7] = f2bf(qv1.w * SCALE);
    qa1u.s[0] = f2bf(qv2.x * SCALE); qa1u.s[1] = f2bf(qv2.y * SCALE);
    qa1u.s[2] = f2bf(qv2.z * SCALE); qa1u.s[3] = f2bf(qv2.w * SCALE);
    qa1u.s[4] = f2bf(qv3.x * SCALE); qa1u.s[5] = f2bf(qv3.y * SCALE);
    qa1u.s[6] = f2bf(qv3.z * SCALE); qa1u.s[7] = f2bf(qv3.w * SCALE);
    const bf16x8 qa0 = qa0u.v, qa1 = qa1u.v;

    // ---- per-lane fragment offsets within one 64-key tile (swizzle folded) ----
    const int s7 = l15 & 7;
    int off[8];
    #pragma unroll
    for (int nt = 0; nt < 4; ++nt) {
        off[nt * 2    ] = (nt * 16 + l15) * 8 + ((quad    ) ^ s7);
        off[nt * 2 + 1] = (nt * 16 + l15) * 8 + ((quad + 4) ^ s7);
    }

    auto loadT = [&](const uint4* base, KF& d) {
        #pragma unroll
        for (int i = 0; i < 8; ++i) d.f[i] = *(const bf16x8*)(base + off[i]);
    };

    // ---- raw mask base for this wave's 16 rows ----
    const int* Mraw = mask + ((size_t)bh * L + row0) * L + lane;

    // stage 16 rows x 64 cols of int32 mask for kt into LDS buf (async, 0 VGPR)
    auto stageM = [&](int kt, unsigned* buf) {
        const int* src = Mraw + kt * 64;
        #pragma unroll
        for (int rr = 0; rr < 16; ++rr)
            __builtin_amdgcn_global_load_lds(
                (const __attribute__((address_space(1))) unsigned int*)(src + (size_t)rr * L),
                (__attribute__((address_space(3))) unsigned int*)(buf + rr * 68), 4, 0, 0);
    };

    unsigned mb[16];                              // bit kt, idx r*4+nt (for pass 2)
    #pragma unroll
    for (int i = 0; i < 16; ++i) mb[i] = 0u;

    // ===================== PASS 1: row sums of exp (+ mask pipeline) =====================
    float lsum[4] = {0.f, 0.f, 0.f, 0.f};

    unsigned* mbuf0 = &sM[w][0][0];
    unsigned* mbuf1 = &sM[w][1][0];
    unsigned* mbuf2 = &sM[w][2][0];
    stageM(0, mbuf0); stageM(1, mbuf1); stageM(2, mbuf2);

    KF kc, kn;
    loadT(gK, kc);

    for (int kt = 0; kt < NKT; ++kt) {
        if (kt + 1 < NKT) loadT(gK + (size_t)(kt + 1) * 512, kn);   // K prefetch

        f32x4 acc[4];
        #pragma unroll
        for (int nt = 0; nt < 4; ++nt) {
            acc[nt] = (f32x4){0.f, 0.f, 0.f, 0.f};
            acc[nt] = __builtin_amdgcn_mfma_f32_16x16x32_bf16(qa0, kc.f[nt*2  ], acc[nt], 0, 0, 0);
            acc[nt] = __builtin_amdgcn_mfma_f32_16x16x32_bf16(qa1, kc.f[nt*2+1], acc[nt], 0, 0, 0);
        }

        // ensure mask stage(kt) has landed (conservative; see header comment)
        asm volatile("s_waitcnt vmcnt(32)" ::: "memory");

        #pragma unroll
        for (int nt = 0; nt < 4; ++nt)
            #pragma unroll
            for (int r = 0; r < 4; ++r) {
                unsigned mv = mbuf0[(quad * 4 + r) * 68 + nt * 16 + l15];
                unsigned bit = mv ? 1u : 0u;
                mb[r * 4 + nt] |= bit << kt;
                float e = __expf(acc[nt][r]);
                lsum[r] += bit ? 0.f : e;
            }

        if (kt + 3 < NKT) stageM(kt + 3, mbuf0);  // refill freed buffer
        unsigned* tmp = mbuf0; mbuf0 = mbuf1; mbuf1 = mbuf2; mbuf2 = tmp;
        if (kt + 1 < NKT) kc = kn;
    }

    // wave-local reduce across the 16 l15 lanes of each quad group
    #pragma unroll
    for (int o = 1; o < 16; o <<= 1)
        #pragma unroll
        for (int r = 0; r < 4; ++r) lsum[r] += __shfl_xor(lsum[r], o, 64);
    float rinv[4];
    #pragma unroll
    for (int r = 0; r < 4; ++r) rinv[r] = 1.0f / lsum[r];

    // ===================== PASS 2: attn + O = P@V (barrier-free) =====================
    f32x4 oacc[4];
    #pragma unroll
    for (int d = 0; d < 4; ++d) oacc[d] = (f32x4){0.f, 0.f, 0.f, 0.f};
    float* Ab = attn + ((size_t)bh * L + row0) * L;

    unsigned short* sw0 = &sP[w][0][0];
    unsigned short* sw1 = &sP[w][1][0];

    KF kc2, kn2, vc;
    loadT(gK, kc2);

    for (int kt = 0; kt < NKT; kt += 2) {
        // ================= even sub-iteration: K=kc2, LDS buf 0 =================
        {
            loadT(gV + (size_t)kt * 512, vc);              // V for this sub-iter
            f32x4 acc[4];
            #pragma unroll
            for (int nt = 0; nt < 4; ++nt) {
                acc[nt] = (f32x4){0.f, 0.f, 0.f, 0.f};
                acc[nt] = __builtin_amdgcn_mfma_f32_16x16x32_bf16(qa0, kc2.f[nt*2  ], acc[nt], 0, 0, 0);
                acc[nt] = __builtin_amdgcn_mfma_f32_16x16x32_bf16(qa1, kc2.f[nt*2+1], acc[nt], 0, 0, 0);
            }
            loadT(gK + (size_t)(kt + 1) * 512, kn2);       // prefetch next K
            #pragma unroll
            for (int nt = 0; nt < 4; ++nt)
                #pragma unroll
                for (int r = 0; r < 4; ++r) {
                    float e = __expf(acc[nt][r]);
                    float pr = (((mb[r * 4 + nt] >> kt) & 1u) ? 0.f : e) * rinv[r];
                    const int row = quad * 4 + r;
                    Ab[(size_t)row * L + kt * 64 + nt * 16 + l15] = pr;
                    sw0[row * 72 + nt * 16 + l15] = (unsigned short)f2bf(pr);
                }
            // same-wave LDS transpose read (compiler inserts lgkmcnt; no barrier)
            const bf16x8 pa0 = *(const bf16x8*)&sw0[l15 * 72 + quad * 8];
            const bf16x8 pa1 = *(const bf16x8*)&sw0[l15 * 72 + quad * 8 + 32];
            #pragma unroll
            for (int d = 0; d < 4; ++d) {
                oacc[d] = __builtin_amdgcn_mfma_f32_16x16x32_bf16(pa0, vc.f[d*2  ], oacc[d], 0, 0, 0);
                oacc[d] = __builtin_amdgcn_mfma_f32_16x16x32_bf16(pa1, vc.f[d*2+1], oacc[d], 0, 0, 0);
            }
        }
        // ================= odd sub-iteration: K=kn2, LDS buf 1 =================
        {
            loadT(gV + (size_t)(kt + 1) * 512, vc);
            f32x4 acc[4];
            #pragma unroll
            for (int nt = 0; nt < 4; ++nt) {
                acc[nt] = (f32x4){0.f, 0.f, 0.f, 0.f};
                acc[nt] = __builtin_amdgcn_mfma_f32_16x16x32_bf16(qa0, kn2.f[nt*2  ], acc[nt], 0, 0, 0);
                acc[nt] = __builtin_amdgcn_mfma_f32_16x16x32_bf16(qa1, kn2.f[nt*2+1], acc[nt], 0, 0, 0);
            }
            if (kt + 2 < NKT) loadT(gK + (size_t)(kt + 2) * 512, kc2);   // prefetch
            #pragma unroll
            for (int nt = 0; nt < 4; ++nt)
                #pragma unroll
                for (int r = 0; r < 4; ++r) {
                    float e = __expf(acc[nt][r]);
                    float pr = (((mb[r * 4 + nt] >> (kt + 1)) & 1u) ? 0.f : e) * rinv[r];
                    const int row = quad * 4 + r;
                    Ab[(size_t)row * L + (kt + 1) * 64 + nt * 16 + l15] = pr;
                    sw1[row * 72 + nt * 16 + l15] = (unsigned short)f2bf(pr);
                }
            const bf16x8 pa0 = *(const bf16x8*)&sw1[l15 * 72 + quad * 8];
            const bf16x8 pa1 = *(const bf16x8*)&sw1[l15 * 72 + quad * 8 + 32];
            #pragma unroll
            for (int d = 0; d < 4; ++d) {
                oacc[d] = __builtin_amdgcn_mfma_f32_16x16x32_bf16(pa0, vc.f[d*2  ], oacc[d], 0, 0, 0);
                oacc[d] = __builtin_amdgcn_mfma_f32_16x16x32_bf16(pa1, vc.f[d*2+1], oacc[d], 0, 0, 0);
            }
        }
    }

    float* Ob = out + ((size_t)bh * L + row0) * D;
    #pragma unroll
    for (int d = 0; d < 4; ++d)
        #pragma unroll
        for (int r = 0; r < 4; ++r)
            Ob[(size_t)(quad * 4 + r) * D + d * 16 + l15] = oacc[d][r];
}

// ===================== fallback (round-1 kernel, known good) ==============

extern "C" __global__ __launch_bounds__(256, 2)
void sdpa_kernel(const float* __restrict__ q, const float* __restrict__ k,
                 const float* __restrict__ v, const int* __restrict__ mask,
                 float* __restrict__ out, float* __restrict__ attn)
{
    __shared__ unsigned short fQ[64 * 72];
    __shared__ unsigned short fK[64 * 72];
    __shared__ unsigned short fVt[64 * 72];
    __shared__ unsigned short fP[64 * 72];
    __shared__ unsigned long long fM[64 * 33];

    const int tid  = threadIdx.x;
    const int lane = tid & 63;
    const int w    = tid >> 6;
    const int quad = lane >> 4;
    const int l15  = lane & 15;

    const int p  = blockIdx.x;
    const int bh = p & (BH - 1);
    const int qb = p >> 4;
    const int q0 = qb * 64;

    const size_t base = (size_t)bh * L * D;
    const float* Qb = q + base + (size_t)q0 * D;
    const float* Kb = k + base;
    const float* Vb = v + base;
    const int*   Mb = mask + (size_t)bh * L * L + (size_t)q0 * L;
    float*       Ab = attn + (size_t)bh * L * L + (size_t)q0 * L;
    float*       Ob = out  + base + (size_t)q0 * D;

    {
        const float2* Qs = (const float2*)Qb;
        for (int i = 0; i < 8; ++i) {
            int idx = i * 256 + tid;
            int row = idx >> 5, d2 = idx & 31;
            float2 val = Qs[idx];
            unsigned pk = f2bf(val.x) | (f2bf(val.y) << 16);
            *(unsigned*)&fQ[row * 72 + d2 * 2] = pk;
        }
    }
    for (int rr = 0; rr < 16; ++rr) {
        int row = w * 16 + rr;
        const int4* Ms = (const int4*)(Mb + (size_t)row * L);
        for (int it = 0; it < 8; ++it) {
            int4 mv = Ms[it * 64 + lane];
            unsigned long long b0 = __ballot(mv.x != 0);
            unsigned long long b1 = __ballot(mv.y != 0);
            unsigned long long b2 = __ballot(mv.z != 0);
            unsigned long long b3 = __ballot(mv.w != 0);
            if (lane == 0) {
                unsigned long long* dst = &fM[row * 33 + it * 4];
                dst[0] = b0; dst[1] = b1; dst[2] = b2; dst[3] = b3;
            }
        }
    }
    __syncthreads();

    const int qrow = w * 16 + l15;
    bf16x8 qa0 = *(const bf16x8*)&fQ[qrow * 72 + quad * 8];
    bf16x8 qa1 = *(const bf16x8*)&fQ[qrow * 72 + quad * 8 + 32];

    float lsum[4] = {0.f, 0.f, 0.f, 0.f};
    for (int kt = 0; kt < 32; ++kt) {
        const int k0 = kt * 64;
        __syncthreads();
        {
            const float2* Ks = (const float2*)(Kb + (size_t)k0 * D);
            for (int i = 0; i < 8; ++i) {
                int idx = i * 256 + tid;
                int row = idx >> 5, d2 = idx & 31;
                float2 val = Ks[idx];
                unsigned pk = f2bf(val.x) | (f2bf(val.y) << 16);
                *(unsigned*)&fK[row * 72 + d2 * 2] = pk;
            }
        }
        __syncthreads();
        f32x4 acc[4];
        for (int nt = 0; nt < 4; ++nt) {
            bf16x8 b0 = *(const bf16x8*)&fK[(nt * 16 + l15) * 72 + quad * 8];
            bf16x8 b1 = *(const bf16x8*)&fK[(nt * 16 + l15) * 72 + quad * 8 + 32];
            f32x4 c = {0.f, 0.f, 0.f, 0.f};
            c = __builtin_amdgcn_mfma_f32_16x16x32_bf16(qa0, b0, c, 0, 0, 0);
            c = __builtin_amdgcn_mfma_f32_16x16x32_bf16(qa1, b1, c, 0, 0, 0);
            acc[nt] = c;
        }
        const int widx = (k0 >> 8) * 4 + (lane & 3);
        const int bsh0 = (k0 >> 2) + (l15 >> 2);
        for (int r = 0; r < 4; ++r) {
            int row = w * 16 + quad * 4 + r;
            unsigned long long mwv = fM[row * 33 + widx];
            float s = 0.f;
            for (int nt = 0; nt < 4; ++nt) {
                float val = acc[nt][r] * SCALE;
                int bit = (int)((mwv >> ((bsh0 + nt * 4) & 63)) & 1ull);
                val = bit ? MASK_FILL : val;
                s += __expf(val);
            }
            lsum[r] += s;
        }
    }
    for (int off = 1; off < 16; off <<= 1)
        for (int r = 0; r < 4; ++r) lsum[r] += __shfl_xor(lsum[r], off, 64);
    float rinv[4];
    for (int r = 0; r < 4; ++r) rinv[r] = 1.0f / lsum[r];

    f32x4 oacc[4];
    for (int nt = 0; nt < 4; ++nt) oacc[nt] = (f32x4){0.f, 0.f, 0.f, 0.f};

    for (int kt = 0; kt < 32; ++kt) {
        const int k0 = kt * 64;
        __syncthreads();
        {
            const float2* Ks = (const float2*)(Kb + (size_t)k0 * D);
            for (int i = 0; i < 8; ++i) {
                int idx = i * 256 + tid;
                int row = idx >> 5, d2 = idx & 31;
                float2 val = Ks[idx];
                unsigned pk = f2bf(val.x) | (f2bf(val.y) << 16);
                *(unsigned*)&fK[row * 72 + d2 * 2] = pk;
            }
        }
        {
            unsigned pk[8];
            for (int jj = 0; jj < 16; ++jj) {
                float val = Vb[(size_t)(k0 + w * 16 + jj) * D + lane];
                unsigned bv = f2bf(val);
                if (jj & 1) pk[jj >> 1] |= bv << 16;
                else        pk[jj >> 1]  = bv;
            }
            uint4* dst = (uint4*)&fVt[lane * 72 + w * 16];
            dst[0] = make_uint4(pk[0], pk[1], pk[2], pk[3]);
            dst[1] = make_uint4(pk[4], pk[5], pk[6], pk[7]);
        }
        __syncthreads();
        f32x4 acc[4];
        for (int nt = 0; nt < 4; ++nt) {
            bf16x8 b0 = *(const bf16x8*)&fK[(nt * 16 + l15) * 72 + quad * 8];
            bf16x8 b1 = *(const bf16x8*)&fK[(nt * 16 + l15) * 72 + quad * 8 + 32];
            f32x4 c = {0.f, 0.f, 0.f, 0.f};
            c = __builtin_amdgcn_mfma_f32_16x16x32_bf16(qa0, b0, c, 0, 0, 0);
            c = __builtin_amdgcn_mfma_f32_16x16x32_bf16(qa1, b1, c, 0, 0, 0);
            acc[nt] = c;
        }
        const int widx = (k0 >> 8) * 4 + (lane & 3);
        const int bsh0 = (k0 >> 2) + (l15 >> 2);
        for (int r = 0; r < 4; ++r) {
            int row = w * 16 + quad * 4 + r;
            unsigned long long mwv = fM[row * 33 + widx];
            for (int nt = 0; nt < 4; ++nt) {
                float val = acc[nt][r] * SCALE;
                int bit = (int)((mwv >> ((bsh0 + nt * 4) & 63)) & 1ull);
                val = bit ? MASK_FILL : val;
                float pr = __expf(val) * rinv[r];
                fP[row * 72 + nt * 16 + l15] = (unsigned short)f2bf(pr);
            }
        }
        for (int it = 0; it < 4; ++it) {
            int row = w * 16 + it * 4 + quad;
            unsigned long long pv = *(const unsigned long long*)&fP[row * 72 + l15 * 4];
            float4 o;
            o.x = bf2f((unsigned short)(pv         & 0xFFFF));
            o.y = bf2f((unsigned short)((pv >> 16) & 0xFFFF));
            o.z = bf2f((unsigned short)((pv >> 32) & 0xFFFF));
            o.w = bf2f((unsigned short)((pv >> 48) & 0xFFFF));
            *(float4*)&Ab[(size_t)row * L + k0 + l15 * 4] = o;
        }
        {
            bf16x8 pa0 = *(const bf16x8*)&fP[qrow * 72 + quad * 8];
            bf16x8 pa1 = *(const bf16x8*)&fP[qrow * 72 + quad * 8 + 32];
            for (int nt = 0; nt < 4; ++nt) {
                bf16x8 vb0 = *(const bf16x8*)&fVt[(nt * 16 + l15) * 72 + quad * 8];
                bf16x8 vb1 = *(const bf16x8*)&fVt[(nt * 16 + l15) * 72 + quad * 8 + 32];
                oacc[nt] = __builtin_amdgcn_mfma_f32_16x16x32_bf16(pa0, vb0, oacc[nt], 0, 0, 0);
                oacc[nt] = __builtin_amdgcn_mfma_f32_16x16x32_bf16(pa1, vb1, oacc[nt], 0, 0, 0);
            }
        }
    }
    for (int nt = 0; nt < 4; ++nt)
        for (int r = 0; r < 4; ++r)
            Ob[(size_t)(w * 16 + quad * 4 + r) * D + nt * 16 + l15] = oacc[nt][r];
}

// ============================== launch ====================================

extern "C" void kernel_launch(void* const* d_in, const int* in_sizes, int n_in,
                              void* d_out, int out_size, void* d_ws, size_t ws_size,
                              hipStream_t stream)
{
    const float* q    = (const float*)d_in[0];
    const float* k    = (const float*)d_in[1];
    const float* v    = (const float*)d_in[2];
    const int*   mask = (const int*)d_in[3];
    float* out  = (float*)d_out;
    float* attn = out + (size_t)BH * L * D;

    const size_t WS_K  = 0;
    const size_t WS_VT = (size_t)BH * L * D * 2;            // 4 MB
    const size_t NEED  = WS_VT + (size_t)BH * L * D * 2;    // 8 MB

    if (ws_size >= NEED) {
        uint4* wsK  = (uint4*)((char*)d_ws + WS_K);
        uint4* wsVt = (uint4*)((char*)d_ws + WS_VT);
        hipLaunchKernelGGL(prep, dim3(1536), dim3(256), 0, stream,
                           k, v, wsK, wsVt);
        hipLaunchKernelGGL(sdpa_main, dim3(BH * (L / QB)), dim3(256), 0, stream,
                           q, (const uint4*)wsK, (const uint4*)wsVt, mask, out, attn);
    } else {
        hipLaunchKernelGGL(sdpa_kernel, dim3(BH * (L / 64)), dim3(256), 0, stream,
                           q, k, v, mask, out, attn);
    }
}